// Round 12
// baseline (2906.226 us; speedup 1.0000x reference)
//
#include <hip/hip_runtime.h>
#include <stdint.h>

#define NB 16
#define HH 128
#define WW 128
#define L (HH*WW)        // 16384
#define CIN 3
#define HID 256
#define NC 21
#define CHUNK 256
#define WARM 512
#define NCHUNKS (L/CHUNK)   // 64
#define T_PER 32            // t's per wave in k_bp
#define NPACK (L/4)         // 4096 packs of 4 timesteps

// ---------------- K1: conv -> fp32 emissions, stored TRANSPOSED em_T[b][c][t] ----------------
// fp64 accumulate (round once to fp32 = correctly rounded), fp32 elementwise bias in ref order.
__global__ __launch_bounds__(256) void k_conv(
    const float* __restrict__ x, const float* __restrict__ w1,
    const float* __restrict__ b1, const float* __restrict__ w2,
    const float* __restrict__ b2, float* __restrict__ emT)
{
    int tid = threadIdx.x;
    int g  = blockIdx.x * 256 + tid;      // 0..B*L-1
    int b  = g >> 14;
    int t  = g & (L-1);
    int y  = t >> 7;
    int xx = t & (WW-1);

    double p[27];
    const float* xb = x + (size_t)b * CIN * L;
    #pragma unroll
    for (int ic = 0; ic < CIN; ++ic) {
        #pragma unroll
        for (int ky = 0; ky < 3; ++ky) {
            #pragma unroll
            for (int kx = 0; kx < 3; ++kx) {
                int yy = y + ky - 1, xc = xx + kx - 1;
                float v = 0.f;
                if (yy >= 0 && yy < HH && xc >= 0 && xc < WW)
                    v = xb[ic * L + yy * WW + xc];
                p[ic*9 + ky*3 + kx] = (double)v;
            }
        }
    }

    double acc[NC];
    #pragma unroll
    for (int c = 0; c < NC; ++c) acc[c] = 0.0;

    // unroll 2: pipelines the wave-uniform (scalar) weight loads behind fp64 FMAs.
    // Per-accumulator FP op order unchanged -> bit-identical results.
    #pragma unroll 2
    for (int oc = 0; oc < HID; ++oc) {
        double hv = 0.0;                              // conv1 accum
        #pragma unroll
        for (int j = 0; j < 27; ++j) hv += (double)w1[oc*27 + j] * p[j];
        float h32 = (float)hv;                        // round conv1 to fp32
        h32 = h32 + b1[oc];                           // fp32 elementwise bias
        h32 = fmaxf(h32, 0.f);                        // relu (fp32)
        double hd = (double)h32;
        #pragma unroll
        for (int c = 0; c < NC; ++c) acc[c] += (double)w2[c*HID + oc] * hd;
    }
    float* dstb = emT + (size_t)b * NC * L;
    #pragma unroll
    for (int c = 0; c < NC; ++c) {
        float e32 = (float)acc[c];                    // round conv2 to fp32
        dstb[(size_t)c * L + t] = e32 + b2[c];        // transposed store (coalesced in t)
    }
}

// ---------------- K2a: sequential fp32 score recursion, 1-level LDS broadcast ----------------
// s'[n] = fl( max_p fl(s[p]+T[p][n]) + e[n] ) — bitwise equal to ref by RNE monotonicity.
// R11 was latency-bound on TWO dependent bpermute levels (~2x120 cyc). Here: ONE cross-lane
// level per step — lane n publishes s[n] via ds_write_b32, all lanes read the full vector
// back via wave-uniform ds_read (1x b32 + 5x b128, broadcast, conflict-free, ~12 cyc issue).
// Same-wave DS ops execute in order -> no barrier needed. Path/step ~ 200 cyc vs R11's 314.
__global__ __launch_bounds__(64) void k_scores(
    const float* __restrict__ emT, const float* __restrict__ start,
    const float* __restrict__ endt, const float* __restrict__ trans,
    float* __restrict__ sc, int* __restrict__ last_tag)
{
    __shared__ float ldsb[24];       // s-vector broadcast buffer (b128-aligned reads)
    int l = threadIdx.x;
    int b = blockIdx.x;

    if (l < NC) {
        int n = l;
        const float4* er4 = (const float4*)(emT + ((size_t)b * NC + n) * L);
        float*        scp = sc + (size_t)b * NC * L;          // 84 floats per pack

        float tc[NC];
        #pragma unroll
        for (int pp = 0; pp < NC; ++pp) tc[pp] = trans[pp*NC + n];
        #pragma unroll
        for (int pp = 0; pp < NC; ++pp) asm volatile("" : "+v"(tc[pp]));  // pin in VGPRs

        float sv;   // my state's current score s[n]

        #define STEP(EV, OUT) { \
            ldsb[n] = sv;                              /* ds_write_b32: publish s[n] */ \
            float  r20 = ldsb[20];                     /* uniform ds_read_b32 (issued first) */ \
            float4 r0  = *(const float4*)(ldsb + 0);   /* uniform ds_read_b128 x5 */ \
            float4 r1  = *(const float4*)(ldsb + 4);   \
            float4 r2  = *(const float4*)(ldsb + 8);   \
            float4 r3  = *(const float4*)(ldsb + 12);  \
            float4 r4  = *(const float4*)(ldsb + 16);  \
            float w0=r0.x+tc[0],  w1=r0.y+tc[1],  w2=r0.z+tc[2],  w3=r0.w+tc[3]; \
            float w4=r1.x+tc[4],  w5=r1.y+tc[5],  w6=r1.z+tc[6],  w7=r1.w+tc[7]; \
            float w8=r2.x+tc[8],  w9=r2.y+tc[9],  wa=r2.z+tc[10], wb=r2.w+tc[11]; \
            float wc=r3.x+tc[12], wd=r3.y+tc[13], we=r3.z+tc[14], wf=r3.w+tc[15]; \
            float wg=r4.x+tc[16], wh=r4.y+tc[17], wi=r4.z+tc[18], wj=r4.w+tc[19]; \
            float wk=r20+tc[20]; \
            float m0 = fmaxf(fmaxf(w0, w1), w2); \
            float m1 = fmaxf(fmaxf(w3, w4), w5); \
            float m2 = fmaxf(fmaxf(w6, w7), w8); \
            float m3 = fmaxf(fmaxf(w9, wa), wb); \
            float m4 = fmaxf(fmaxf(wc, wd), we); \
            float m5 = fmaxf(fmaxf(wf, wg), wh); \
            float m6 = fmaxf(fmaxf(wi, wj), wk); \
            float a0 = fmaxf(fmaxf(m0, m1), m2); \
            float a1 = fmaxf(fmaxf(m3, m4), m5); \
            OUT = fmaxf(fmaxf(a0, a1), m6) + (EV);     /* exact 21-max, then fl(+e) */ \
            sv = OUT; }

        float4 ebuf0 = er4[0];
        float4 ebuf1 = er4[1];

        // ---- pack 0 (t=0 init + t=1..3) ----
        float v0 = ebuf0.x + start[n];      // s0 = fl(em[0]+start), ref order
        sv = v0;
        {
            float4 ev = ebuf0;
            ebuf0 = er4[2];
            float a1v, a2v, a3v;
            STEP(ev.y, a1v)
            STEP(ev.z, a2v)
            STEP(ev.w, a3v)
            *(float4*)(scp + n*4) = make_float4(v0, a1v, a2v, a3v);
        }

        // ---- packs 1..4095 ----
        for (int k = 1; k < NPACK; ++k) {
            float4 ev = (k & 1) ? ebuf1 : ebuf0;
            int kp = k + 2; if (kp > NPACK-1) kp = NPACK-1;
            if (k & 1) ebuf1 = er4[kp]; else ebuf0 = er4[kp];

            float b0, b1_, b2_, b3;
            STEP(ev.x, b0)
            STEP(ev.y, b1_)
            STEP(ev.z, b2_)
            STEP(ev.w, b3)
            *(float4*)(scp + k*84 + n*4) = make_float4(b0, b1_, b2_, b3);
        }
        #undef STEP

        // final tag: publish s_{L-1}, lane 0 does first-index argmax of s + end
        ldsb[n] = sv;                       // ds_write; same-wave in-order w.r.t. reads below
        if (n == 0) {
            float bv = ldsb[0] + endt[0]; int bt = 0;
            #pragma unroll
            for (int j = 1; j < NC; ++j) {
                float v = ldsb[j] + endt[j];
                if (v > bv) { bv = v; bt = j; }
            }
            last_tag[b] = bt;
        }
    }
}

// ---------------- K2b: parallel backpointer recovery ----------------
// bp[t][n] = first p with fl(fl(s_{t-1}[p]+T[p][n])+e[t][n]) == s_t[n]
__global__ __launch_bounds__(256) void k_bp(
    const float* __restrict__ emT, const float* __restrict__ sc,
    const float* __restrict__ trans, uint8_t* __restrict__ bp)
{
    int wave = threadIdx.x >> 6;
    int lane = threadIdx.x & 63;
    int ne   = lane < NC ? lane : NC-1;

    int bidx  = blockIdx.x;
    int b     = bidx >> 7;                              // 128 blocks per batch
    int tbase = (bidx & 127) * (4*T_PER) + wave*T_PER;

    const float* emb = emT + (size_t)b * NC * L;
    const float* scp = sc  + (size_t)b * NC * L;
    uint8_t*     bpb = bp  + (size_t)b * L * NC;

    float tc[NC];
    #pragma unroll
    for (int pp = 0; pp < NC; ++pp) tc[pp] = trans[pp*NC + ne];

    for (int t = tbase; t < tbase + T_PER; ++t) {
        if (t == 0) continue;
        float target = scp[(t>>2)*84 + ne*4 + (t&3)];
        float e      = emb[(size_t)ne * L + t];
        const float* sp = scp + ((t-1)>>2)*84 + ((t-1)&3);
        int fi = 0;
        #pragma unroll
        for (int pp = NC-1; pp >= 0; --pp) {
            float cand = (sp[pp*4] + tc[pp]) + e;
            if (cand == target) fi = pp;
        }
        if (lane < NC) bpb[(size_t)t * NC + ne] = (uint8_t)fi;
    }
}

// ---------------- K3: chunk-parallel backtrack (integer, exact) ----------------
__global__ __launch_bounds__(64) void k_backtrack(
    const uint8_t* __restrict__ bp, const int* __restrict__ last_tag,
    int* __restrict__ out)
{
    int blk = blockIdx.x;
    int b   = blk >> 6;
    int k   = blk & (NCHUNKS-1);
    int cs  = k * CHUNK;
    int ce  = cs + CHUNK;
    int sp  = ce - 1 + WARM; if (sp > L-1) sp = L-1;
    int tag = (sp == L-1) ? last_tag[b] : 0;
    const uint8_t* bpb = bp + (size_t)b * L * NC;
    int* ob = out + (size_t)b * L;
    for (int t = sp;; --t) {
        if (t < ce) { if (threadIdx.x == 0) ob[t] = tag; }
        if (t == cs) break;
        tag = (int)bpb[(size_t)t * NC + tag];
    }
}

extern "C" void kernel_launch(void* const* d_in, const int* in_sizes, int n_in,
                              void* d_out, int out_size, void* d_ws, size_t ws_size,
                              hipStream_t stream) {
    const float* x  = (const float*)d_in[0];
    const float* w1 = (const float*)d_in[1];
    const float* b1 = (const float*)d_in[2];
    const float* w2 = (const float*)d_in[3];
    const float* b2 = (const float*)d_in[4];
    const float* st = (const float*)d_in[5];
    const float* en = (const float*)d_in[6];
    const float* tr = (const float*)d_in[7];
    int* out = (int*)d_out;

    char* ws = (char*)d_ws;
    float*   em = (float*)ws;                                    // em_T: 22,020,096 B
    float*   sc = (float*)(ws + (size_t)NB*L*NC*4);              // packed scores: 22,020,096 B
    uint8_t* bp = (uint8_t*)(ws + (size_t)NB*L*NC*8);            // 5,505,024 B
    int*     lt = (int*)(ws + (size_t)NB*L*NC*9);                // int[NB]

    k_conv     <<<dim3(NB*L/256),   dim3(256), 0, stream>>>(x, w1, b1, w2, b2, em);
    k_scores   <<<dim3(NB),         dim3(64),  0, stream>>>(em, st, en, tr, sc, lt);
    k_bp       <<<dim3(NB*128),     dim3(256), 0, stream>>>(em, sc, tr, bp);
    k_backtrack<<<dim3(NB*NCHUNKS), dim3(64),  0, stream>>>(bp, lt, out);
}